// Round 9
// baseline (41.183 us; speedup 1.0000x reference)
//
#include <hip/hip_runtime.h>
#include <hip/hip_bf16.h>

// Problem: B=24, L=512, D=64, H=64
//   h = gelu(x @ W + b); S = h_i h_j^T per pair; scores = logsumexp(S).
// scores = log(sum 2^(S*log2e)); B operand pre-scaled by log2e. 300
// unique (i<=j) pairs, mirrored at the end.
//
// R9 PROBE: identical to R8 except pair_kernel is dispatched TWICE
// (idempotent rewrite of the same part values — deterministic).
// dur(R9) - dur(R8) = true marginal cost of one pair dispatch.
//   Δ≈18-20us -> pair is intra-kernel stall-bound (R10: asm pipeline).
//   Δ≈8-11us  -> ~half our total is dispatch overhead (R10: fuse kernels).

#define LOG2E 1.4426950408889634f

typedef unsigned short u16;
typedef __attribute__((ext_vector_type(8))) short bf16x8;
typedef __attribute__((ext_vector_type(4))) float f32x4;

static __device__ __forceinline__ u16 bf16bits(float f) {
  __hip_bfloat16 h = __float2bfloat16(f);
  return *reinterpret_cast<u16*>(&h);
}

// Schraudolph fast 2^x: valid for x in (-126, 128), rel err <= 3.04%.
static __device__ __forceinline__ float fast_exp2(float x) {
  int i = (int)fmaf(x, 8388608.0f, 1065098601.0f);
  return __int_as_float(i);
}

// ---------------- encoder: h = gelu(x@W+b) via MFMA -----------------------
__global__ __launch_bounds__(256) void encode_kernel(
    const float* __restrict__ x, const float* __restrict__ W,
    const float* __restrict__ bias, u16* __restrict__ hb,
    u16* __restrict__ hlb) {
  int lane = threadIdx.x & 63;
  int wid = threadIdx.x >> 6;
  int row0 = (blockIdx.x * 4 + wid) * 16;      // 12288 rows / 16 = 768 waves
  int r = lane & 15;
  int kg = lane >> 4;

  bf16x8 xa[2];
#pragma unroll
  for (int kh = 0; kh < 2; ++kh) {
    const float* xp = x + (size_t)(row0 + r) * 64 + kh * 32 + kg * 8;
    bf16x8 v;
#pragma unroll
    for (int e = 0; e < 8; ++e) v[e] = (short)bf16bits(xp[e]);
    xa[kh] = v;
  }

  bf16x8 wf[4][2];
#pragma unroll
  for (int nb = 0; nb < 4; ++nb)
#pragma unroll
    for (int kh = 0; kh < 2; ++kh) {
      bf16x8 v;
#pragma unroll
      for (int e = 0; e < 8; ++e)
        v[e] = (short)bf16bits(W[(kh * 32 + kg * 8 + e) * 64 + nb * 16 + r]);
      wf[nb][kh] = v;
    }

  const f32x4 zero = {0.f, 0.f, 0.f, 0.f};
#pragma unroll
  for (int nb = 0; nb < 4; ++nb) {
    f32x4 acc = __builtin_amdgcn_mfma_f32_16x16x32_bf16(xa[0], wf[nb][0], zero, 0, 0, 0);
    acc = __builtin_amdgcn_mfma_f32_16x16x32_bf16(xa[1], wf[nb][1], acc, 0, 0, 0);
    float bb = bias[nb * 16 + r];
#pragma unroll
    for (int q = 0; q < 4; ++q) {
      float z = acc[q] + bb;
      float t = tanhf(0.7978845608028654f * (z + 0.044715f * z * z * z));
      float g = 0.5f * z * (1.0f + t);
      size_t o = (size_t)(row0 + kg * 4 + q) * 64 + nb * 16 + r;
      hb[o] = bf16bits(g);
      hlb[o] = bf16bits(g * LOG2E);
    }
  }
}

// ---------------- pair kernel (identical to R8) ---------------------------
__global__ __launch_bounds__(256) void pair_kernel(
    const u16* __restrict__ hb, const u16* __restrict__ hlb,
    float* __restrict__ part) {
  __shared__ char smem[32768];

  int idx = blockIdx.x;
  int p = idx >> 2;
  int tile = idx & 3;
  int rh = tile >> 1;          // row half of A (256 rows)
  int ch = tile & 1;           // col half of B (256 rows)
  int i = 0, rem = p;
  while (rem >= 24 - i) { rem -= 24 - i; ++i; }
  int j = i + rem;

  const u16* Ap = hb + (size_t)i * 512 * 64;
  const char* Bbytes =
      (const char*)(hlb + (size_t)j * 512 * 64) + (size_t)ch * 256 * 128;

  int wid = threadIdx.x >> 6;
  int lane = threadIdx.x & 63;
  int r = lane & 15;
  int kg = lane >> 4;
  int row0 = rh * 256 + wid * 64;

  bf16x8 a[4][2];
#pragma unroll
  for (int rm = 0; rm < 4; ++rm)
#pragma unroll
    for (int kf = 0; kf < 2; ++kf)
      a[rm][kf] = *reinterpret_cast<const bf16x8*>(
          Ap + (size_t)(row0 + rm * 16 + r) * 64 + kf * 32 + kg * 8);

#pragma unroll
  for (int c = 0; c < 8; ++c) {
    int obase = (wid * 8 + c) * 1024;
    int o = obase + lane * 16;
    int src = o ^ (((o >> 7) & 7) << 4);
    __builtin_amdgcn_global_load_lds(
        (const __attribute__((address_space(1))) void*)(Bbytes + src),
        (__attribute__((address_space(3))) void*)(smem + obase), 16, 0, 0);
  }

  int sw = (r & 7) << 4;
  int off0 = r * 128 + ((kg * 16) ^ sw);
  int off1 = r * 128 + ((64 + kg * 16) ^ sw);

  __syncthreads();

  float s0 = 0.f, s1 = 0.f, s2 = 0.f, s3 = 0.f;
  const f32x4 zero = {0.f, 0.f, 0.f, 0.f};

#pragma unroll
  for (int cn = 0; cn < 16; ++cn) {
    const char* bp = smem + cn * 2048;
    bf16x8 b0 = *reinterpret_cast<const bf16x8*>(bp + off0);
    bf16x8 b1 = *reinterpret_cast<const bf16x8*>(bp + off1);
#pragma unroll
    for (int rm = 0; rm < 4; ++rm) {
      f32x4 acc = __builtin_amdgcn_mfma_f32_16x16x32_bf16(a[rm][0], b0, zero, 0, 0, 0);
      acc = __builtin_amdgcn_mfma_f32_16x16x32_bf16(a[rm][1], b1, acc, 0, 0, 0);
      s0 += fast_exp2(acc[0]);
      s1 += fast_exp2(acc[1]);
      s2 += fast_exp2(acc[2]);
      s3 += fast_exp2(acc[3]);
    }
  }
  float sum = (s0 + s1) + (s2 + s3);
#pragma unroll
  for (int off = 32; off >= 1; off >>= 1) sum += __shfl_xor(sum, off, 64);
  if (lane == 0) part[idx * 4 + wid] = sum;
}

// ---------------- finalize: sum 16 partials per pair, log, mirror ---------
__global__ void finish_kernel(const float* __restrict__ part,
                              float* __restrict__ out) {
  int t = threadIdx.x + blockIdx.x * blockDim.x;
  if (t >= 576) return;
  int i = t / 24, j = t % 24;
  int ii = i < j ? i : j, jj = i < j ? j : i;
  int p = ii * 24 - ii * (ii - 1) / 2 + (jj - ii);
  const f32x4* pv = reinterpret_cast<const f32x4*>(part + p * 16);
  float s = 0.f;
#pragma unroll
  for (int q = 0; q < 4; ++q) {
    f32x4 v = pv[q];
    s += (v[0] + v[1]) + (v[2] + v[3]);
  }
  out[t] = logf(s);
}

extern "C" void kernel_launch(void* const* d_in, const int* in_sizes, int n_in,
                              void* d_out, int out_size, void* d_ws,
                              size_t ws_size, hipStream_t stream) {
  const float* x = (const float*)d_in[0];
  const float* W = (const float*)d_in[1];
  const float* bias = (const float*)d_in[2];
  float* out = (float*)d_out;

  u16* hb = (u16*)d_ws;                      // 12288*64 bf16 = 1.50 MiB
  u16* hlb = hb + 12288 * 64;                // 1.50 MiB
  float* part = (float*)(hlb + 12288 * 64);  // 1200 * 4 = 4800 f32

  encode_kernel<<<192, 256, 0, stream>>>(x, W, bias, hb, hlb);
  // PROBE: two identical, idempotent pair dispatches. Graph-time delta
  // vs R8 isolates one dispatch's true steady-state cost.
  pair_kernel<<<1200, 256, 0, stream>>>(hb, hlb, part);
  pair_kernel<<<1200, 256, 0, stream>>>(hb, hlb, part);
  finish_kernel<<<9, 64, 0, stream>>>(part, out);
}